// Round 3
// baseline (554.579 us; speedup 1.0000x reference)
//
#include <hip/hip_runtime.h>
#include <hip/hip_bf16.h>
#include <stdint.h>

#define N_NODES 50000
#define N_EDGES 800000
#define IN_FEAT 256
#define OUT_FEAT 256
#define NUM_RELS 64
#define NUM_BASES 8
#define KTOT 2304           // Wt row stride: 8*256 + 256 self-loop
#define KAGG 2048           // A matrix K (bases only)
#define MP 50048            // 391 * 128 padded M
#define SCAN_BLKS 196

typedef __attribute__((ext_vector_type(8))) __bf16 bf16x8;
typedef __attribute__((ext_vector_type(4))) __bf16 bf16x4;
typedef __attribute__((ext_vector_type(4))) float f32x4;
typedef __attribute__((ext_vector_type(2))) float f32x2;

static __device__ __forceinline__ void gload_lds16(const void* g, void* l) {
  auto gp = (const __attribute__((address_space(1))) void*)(uintptr_t)g;
  auto lp = (__attribute__((address_space(3))) void*)(uint32_t)(uintptr_t)l;
  __builtin_amdgcn_global_load_lds(gp, lp, 16, 0, 0);
}

// ---------------- x -> bf16 ----------------
__global__ void k_prex(const float* __restrict__ x, __bf16* __restrict__ xb) {
  int i = blockIdx.x * 256 + threadIdx.x;
  const float4* xp = (const float4*)x;
  float4 u = xp[i * 2], v = xp[i * 2 + 1];
  bf16x8 o;
  o[0] = (__bf16)u.x; o[1] = (__bf16)u.y; o[2] = (__bf16)u.z; o[3] = (__bf16)u.w;
  o[4] = (__bf16)v.x; o[5] = (__bf16)v.y; o[6] = (__bf16)v.z; o[7] = (__bf16)v.w;
  *(bf16x8*)(xb + (size_t)i * 8) = o;
}

// ---------------- CSR build ----------------
__global__ void k_count(const int* __restrict__ dst, int* __restrict__ deg) {
  int e = blockIdx.x * 256 + threadIdx.x;
  atomicAdd(&deg[dst[e]], 1);
}

__global__ void k_scan1(const int* __restrict__ deg, int* __restrict__ offs,
                        int* __restrict__ bsum) {
  __shared__ int s[256];
  int t = threadIdx.x;
  int i = blockIdx.x * 256 + t;
  int v = (i < N_NODES) ? deg[i] : 0;
  s[t] = v;
  __syncthreads();
  for (int d = 1; d < 256; d <<= 1) {
    int y = (t >= d) ? s[t - d] : 0;
    __syncthreads();
    s[t] += y;
    __syncthreads();
  }
  if (i < N_NODES) offs[i] = s[t] - v;
  if (t == 255) bsum[blockIdx.x] = s[255];
}

// adds cross-block base (computed in-block from bsum) and inits fill
__global__ void k_scan3(int* __restrict__ offs, const int* __restrict__ bsum,
                        int* __restrict__ fill) {
  __shared__ int s[256];
  int t = threadIdx.x;
  s[t] = (t < SCAN_BLKS && t < blockIdx.x) ? bsum[t] : 0;
  __syncthreads();
  for (int d = 128; d; d >>= 1) {
    if (t < d) s[t] += s[t + d];
    __syncthreads();
  }
  int base = s[0];
  int i = blockIdx.x * 256 + t;
  if (i < N_NODES) {
    int o = offs[i] + base;
    offs[i] = o;
    fill[i] = o;
  }
}

// scatter packed edge records {src|ety<<16, norm} into CSR order
__global__ void k_scatter(const int* __restrict__ dst, const int* __restrict__ srcv,
                          const int* __restrict__ ety, const float* __restrict__ norm,
                          int* __restrict__ fill, uint2* __restrict__ erec) {
  int e = blockIdx.x * 256 + threadIdx.x;
  int pos = atomicAdd(&fill[dst[e]], 1);
  erec[pos] = make_uint2((unsigned)srcv[e] | ((unsigned)ety[e] << 16),
                         __float_as_uint(norm[e]));
}

// ---------------- aggregation: TWO waves per node ----------------
// lane owns 4 consecutive features; each wave does half the edge list;
// halves exchange the partner's 4-basis group via LDS and store their own.
__global__ __launch_bounds__(256) void k_agg(
    const __bf16* __restrict__ xb, const float* __restrict__ w_comp,
    const int* __restrict__ offs, const int* __restrict__ fin,
    const uint2* __restrict__ erec, __bf16* __restrict__ A) {
  __shared__ float wc[NUM_RELS * NUM_BASES];
  __shared__ float sx[4 * 64 * 17];              // 17-stride: conflict-free
  int t = threadIdx.x;
  wc[t] = w_comp[t];
  wc[t + 256] = w_comp[t + 256];
  __syncthreads();

  int wid = t >> 6, lane = t & 63;
  int p = wid >> 1, h = wid & 1;
  int node = blockIdx.x * 2 + p;                 // grid 25000 -> 50000 nodes

  f32x2 acc[NUM_BASES][2];
#pragma unroll
  for (int b = 0; b < NUM_BASES; ++b) {
    acc[b][0] = f32x2{0.f, 0.f};
    acc[b][1] = f32x2{0.f, 0.f};
  }

  int i0 = offs[node];
  int cnt = fin[node] - i0;
  int c0 = (cnt + 1) >> 1;
  int myn = h ? (cnt - c0) : c0;
  const uint2* rp = erec + i0 + h * c0;
  int lo4 = lane * 4;

  int i = 0;
  for (; i + 4 <= myn; i += 4) {
    uint2 r[4];
#pragma unroll
    for (int j = 0; j < 4; ++j) r[j] = rp[i + j];
    uint2 xv[4];
#pragma unroll
    for (int j = 0; j < 4; ++j)
      xv[j] = *(const uint2*)(xb + (size_t)(r[j].x & 0xffff) * IN_FEAT + lo4);
#pragma unroll
    for (int j = 0; j < 4; ++j) {
      int et = r[j].x >> 16;
      float nm = __uint_as_float(r[j].y);
      f32x2 v0 = {__uint_as_float(xv[j].x << 16) * nm,
                  __uint_as_float(xv[j].x & 0xffff0000u) * nm};
      f32x2 v1 = {__uint_as_float(xv[j].y << 16) * nm,
                  __uint_as_float(xv[j].y & 0xffff0000u) * nm};
      f32x4 cl = *(const f32x4*)&wc[et * 8];
      f32x4 ch = *(const f32x4*)&wc[et * 8 + 4];
#pragma unroll
      for (int b = 0; b < 4; ++b) {
        acc[b][0] += v0 * cl[b];
        acc[b][1] += v1 * cl[b];
        acc[b + 4][0] += v0 * ch[b];
        acc[b + 4][1] += v1 * ch[b];
      }
    }
  }
  for (; i < myn; ++i) {
    uint2 r = rp[i];
    int et = r.x >> 16;
    float nm = __uint_as_float(r.y);
    uint2 xv = *(const uint2*)(xb + (size_t)(r.x & 0xffff) * IN_FEAT + lo4);
    f32x2 v0 = {__uint_as_float(xv.x << 16) * nm,
                __uint_as_float(xv.x & 0xffff0000u) * nm};
    f32x2 v1 = {__uint_as_float(xv.y << 16) * nm,
                __uint_as_float(xv.y & 0xffff0000u) * nm};
    f32x4 cl = *(const f32x4*)&wc[et * 8];
    f32x4 ch = *(const f32x4*)&wc[et * 8 + 4];
#pragma unroll
    for (int b = 0; b < 4; ++b) {
      acc[b][0] += v0 * cl[b];
      acc[b][1] += v1 * cl[b];
      acc[b + 4][0] += v0 * ch[b];
      acc[b + 4][1] += v1 * ch[b];
    }
  }

  // write partner-group bases (the 4 bases the OTHER wave will store)
  float* slot = &sx[(size_t)wid * 64 * 17 + lane * 17];
  int og = (1 - h) * 4;
#pragma unroll
  for (int b = 0; b < 4; ++b) {
    slot[b * 4 + 0] = acc[og + b][0][0];
    slot[b * 4 + 1] = acc[og + b][0][1];
    slot[b * 4 + 2] = acc[og + b][1][0];
    slot[b * 4 + 3] = acc[og + b][1][1];
  }
  __syncthreads();
  const float* ps = &sx[(size_t)(wid ^ 1) * 64 * 17 + lane * 17];
  int mg = h * 4;
  __bf16* Ar = A + (size_t)node * KAGG + lo4;
#pragma unroll
  for (int b = 0; b < 4; ++b) {
    bf16x4 o;
    o[0] = (__bf16)(acc[mg + b][0][0] + ps[b * 4 + 0]);
    o[1] = (__bf16)(acc[mg + b][0][1] + ps[b * 4 + 1]);
    o[2] = (__bf16)(acc[mg + b][1][0] + ps[b * 4 + 2]);
    o[3] = (__bf16)(acc[mg + b][1][1] + ps[b * 4 + 3]);
    *(bf16x4*)(Ar + (mg + b) * 256) = o;
  }
}

// ---------------- weight prep: Wt[o][r] = Wcat[r][o] in bf16 ----------------
__global__ void k_prepw(const float* __restrict__ weight, const float* __restrict__ loop_w,
                        __bf16* __restrict__ Wt) {
  int o = blockIdx.x;
  int t = threadIdx.x;
#pragma unroll
  for (int c = 0; c < 9; ++c) {
    int r = c * 256 + t;
    float v = (r < 2048) ? weight[(size_t)r * 256 + o]
                         : loop_w[(size_t)(r - 2048) * 256 + o];
    Wt[(size_t)o * KTOT + r] = (__bf16)v;
  }
}

// ---------------- GEMM: out[M][256] = [A | xb] @ Wt^T + bias, relu ----------
// 128x256 tile, 4 waves (each 64 rows x 128 cols = 4x8 frags), BK=32.
// LDS XOR-swizzled via pre-swizzled global source (rule 21):
//   physical chunk p of row holds logical chunk q = p ^ ((row>>1)&3).
__global__ __launch_bounds__(256, 2) void k_gemm(const __bf16* __restrict__ A,
                                                 const __bf16* __restrict__ xb,
                                                 const __bf16* __restrict__ Wt,
                                                 const float* __restrict__ bias,
                                                 float* __restrict__ out) {
  __shared__ __align__(16) __bf16 sA[128 * 32];   // 8KB
  __shared__ __align__(16) __bf16 sB[256 * 32];   // 16KB

  int t = threadIdx.x;
  int wid = t >> 6, lane = t & 63;
  int tm = blockIdx.x;
  int wr = wid >> 1, wc = wid & 1;
  int rfw = __builtin_amdgcn_readfirstlane(wid);

  f32x4 acc[4][8];
#pragma unroll
  for (int m = 0; m < 4; ++m)
#pragma unroll
    for (int n = 0; n < 8; ++n) acc[m][n] = f32x4{0.f, 0.f, 0.f, 0.f};

  int frow = lane & 15;
  int kb = (((lane >> 4) ^ ((frow >> 1) & 3)) << 4);  // swizzled k-slice byte off

  // precompute per-thread staging sources (swizzled global chunk addresses)
  const __bf16* gaP[2];
  const __bf16* gxP[2];
#pragma unroll
  for (int it = 0; it < 2; ++it) {
    int L = it * 256 + t;
    int row = L >> 2;
    int q = (L & 3) ^ ((row >> 1) & 3);
    gaP[it] = A + (size_t)(tm * 128 + row) * KAGG + q * 8;
    gxP[it] = xb + (size_t)(tm * 128 + row) * IN_FEAT + q * 8;
  }
  const __bf16* gbP[4];
#pragma unroll
  for (int it = 0; it < 4; ++it) {
    int L = it * 256 + t;
    int row = L >> 2;
    int q = (L & 3) ^ ((row >> 1) & 3);
    gbP[it] = Wt + (size_t)row * KTOT + q * 8;
  }

#define KSTEP(A0, A1, K0)                                                   \
  do {                                                                      \
    gload_lds16((A0), (char*)sA + rfw * 1024);                              \
    gload_lds16((A1), (char*)sA + 4096 + rfw * 1024);                       \
    _Pragma("unroll") for (int it = 0; it < 4; ++it)                        \
        gload_lds16(gbP[it] + (K0), (char*)sB + (it * 256 + rfw * 64) * 16);\
    __syncthreads();                                                        \
    bf16x8 af[4], bfr[8];                                                   \
    _Pragma("unroll") for (int m = 0; m < 4; ++m)                           \
        af[m] = *(const bf16x8*)((const char*)sA +                          \
                                 (wr * 64 + m * 16 + frow) * 64 + kb);      \
    _Pragma("unroll") for (int n = 0; n < 8; ++n)                           \
        bfr[n] = *(const bf16x8*)((const char*)sB +                         \
                                  (wc * 128 + n * 16 + frow) * 64 + kb);    \
    _Pragma("unroll") for (int m = 0; m < 4; ++m)                           \
        _Pragma("unroll") for (int n = 0; n < 8; ++n)                       \
            acc[m][n] = __builtin_amdgcn_mfma_f32_16x16x32_bf16(            \
                af[m], bfr[n], acc[m][n], 0, 0, 0);                         \
    __syncthreads();                                                        \
  } while (0)

  for (int kt = 0; kt < 64; ++kt) {
    int k0 = kt * 32;
    KSTEP(gaP[0] + k0, gaP[1] + k0, k0);
  }
  for (int kt = 64; kt < 72; ++kt) {
    int k0 = kt * 32;
    int kx = k0 - KAGG;
    KSTEP(gxP[0] + kx, gxP[1] + kx, k0);
  }
#undef KSTEP

  // epilogue: C/D layout col = lane&15, row = (lane>>4)*4 + r
  int r0 = (lane >> 4) * 4;
  int c0 = lane & 15;
#pragma unroll
  for (int m = 0; m < 4; ++m) {
    int rowb = tm * 128 + wr * 64 + m * 16 + r0;
#pragma unroll
    for (int n = 0; n < 8; ++n) {
      int col = wc * 128 + n * 16 + c0;
      float bv = bias[col];
#pragma unroll
      for (int r = 0; r < 4; ++r) {
        int row = rowb + r;
        if (row < N_NODES) {
          float v = acc[m][n][r] + bv;
          out[(size_t)row * OUT_FEAT + col] = v > 0.f ? v : 0.f;
        }
      }
    }
  }
}

extern "C" void kernel_launch(void* const* d_in, const int* in_sizes, int n_in,
                              void* d_out, int out_size, void* d_ws, size_t ws_size,
                              hipStream_t stream) {
  const float* x      = (const float*)d_in[0];
  const int*   src    = (const int*)d_in[1];
  const int*   dst    = (const int*)d_in[2];
  const int*   ety    = (const int*)d_in[3];
  const float* norm   = (const float*)d_in[4];
  const float* weight = (const float*)d_in[5];
  const float* w_comp = (const float*)d_in[6];
  const float* h_bias = (const float*)d_in[7];
  const float* loop_w = (const float*)d_in[8];
  float* out = (float*)d_out;

  char* ws = (char*)d_ws;
  __bf16* A  = (__bf16*)ws;                                 // 205MB
  size_t off = (size_t)MP * KAGG * 2;
  __bf16* xb = (__bf16*)(ws + off);                         // 25.6MB
  off += (size_t)MP * IN_FEAT * 2;
  __bf16* Wt = (__bf16*)(ws + off);                         // 1.18MB
  off += (size_t)256 * KTOT * 2;
  uint2* erec = (uint2*)(ws + off);                         // 6.4MB
  off += (size_t)N_EDGES * 8;
  int* deg   = (int*)(ws + off);
  int* offs  = deg + N_NODES;
  int* fill  = offs + N_NODES;
  int* bsum  = fill + N_NODES;

  hipMemsetAsync(deg, 0, N_NODES * sizeof(int), stream);
  k_prex<<<(N_NODES * IN_FEAT / 8) / 256, 256, 0, stream>>>(x, xb);
  k_count<<<N_EDGES / 256, 256, 0, stream>>>(dst, deg);
  k_scan1<<<SCAN_BLKS, 256, 0, stream>>>(deg, offs, bsum);
  k_scan3<<<SCAN_BLKS, 256, 0, stream>>>(offs, bsum, fill);
  k_scatter<<<N_EDGES / 256, 256, 0, stream>>>(dst, src, ety, norm, fill, erec);
  k_agg<<<N_NODES / 2, 256, 0, stream>>>(xb, w_comp, offs, fill, erec, A);
  k_prepw<<<256, 256, 0, stream>>>(weight, loop_w, Wt);
  k_gemm<<<MP / 128, 256, 0, stream>>>(A, xb, Wt, h_bias, out);
}

// Round 4
// 319.773 us; speedup vs baseline: 1.7343x; 1.7343x over previous
//
#include <hip/hip_runtime.h>
#include <hip/hip_bf16.h>
#include <stdint.h>

#define N_NODES 50000
#define N_EDGES 800000
#define IN_FEAT 256
#define OUT_FEAT 256
#define NUM_RELS 64
#define NUM_BASES 8
#define KTOT 2304           // Wt row stride: 8*256 + 256 self-loop
#define KAGG 2048           // A matrix K (bases only)
#define MP 50048            // 391 * 128 padded M
#define SCAN_BLKS 196

typedef __attribute__((ext_vector_type(8))) __bf16 bf16x8;
typedef __attribute__((ext_vector_type(4))) __bf16 bf16x4;
typedef __attribute__((ext_vector_type(4))) float f32x4;
typedef __attribute__((ext_vector_type(2))) float f32x2;

static __device__ __forceinline__ void gload_lds16(const void* g, void* l) {
  auto gp = (const __attribute__((address_space(1))) void*)(uintptr_t)g;
  auto lp = (__attribute__((address_space(3))) void*)(uint32_t)(uintptr_t)l;
  __builtin_amdgcn_global_load_lds(gp, lp, 16, 0, 0);
}

// ---------------- x -> bf16 ----------------
__global__ void k_prex(const float* __restrict__ x, __bf16* __restrict__ xb) {
  int i = blockIdx.x * 256 + threadIdx.x;
  const float4* xp = (const float4*)x;
  float4 u = xp[i * 2], v = xp[i * 2 + 1];
  bf16x8 o;
  o[0] = (__bf16)u.x; o[1] = (__bf16)u.y; o[2] = (__bf16)u.z; o[3] = (__bf16)u.w;
  o[4] = (__bf16)v.x; o[5] = (__bf16)v.y; o[6] = (__bf16)v.z; o[7] = (__bf16)v.w;
  *(bf16x8*)(xb + (size_t)i * 8) = o;
}

// ---------------- CSR build ----------------
__global__ void k_count(const int* __restrict__ dst, int* __restrict__ deg) {
  int e = blockIdx.x * 256 + threadIdx.x;
  atomicAdd(&deg[dst[e]], 1);
}

__global__ void k_scan1(const int* __restrict__ deg, int* __restrict__ offs,
                        int* __restrict__ bsum) {
  __shared__ int s[256];
  int t = threadIdx.x;
  int i = blockIdx.x * 256 + t;
  int v = (i < N_NODES) ? deg[i] : 0;
  s[t] = v;
  __syncthreads();
  for (int d = 1; d < 256; d <<= 1) {
    int y = (t >= d) ? s[t - d] : 0;
    __syncthreads();
    s[t] += y;
    __syncthreads();
  }
  if (i < N_NODES) offs[i] = s[t] - v;
  if (t == 255) bsum[blockIdx.x] = s[255];
}

// adds cross-block base (computed in-block from bsum) and inits fill
__global__ void k_scan3(int* __restrict__ offs, const int* __restrict__ bsum,
                        int* __restrict__ fill) {
  __shared__ int s[256];
  int t = threadIdx.x;
  s[t] = (t < SCAN_BLKS && t < blockIdx.x) ? bsum[t] : 0;
  __syncthreads();
  for (int d = 128; d; d >>= 1) {
    if (t < d) s[t] += s[t + d];
    __syncthreads();
  }
  int base = s[0];
  int i = blockIdx.x * 256 + t;
  if (i < N_NODES) {
    int o = offs[i] + base;
    offs[i] = o;
    fill[i] = o;
  }
}

// scatter packed edge records {src|ety<<16, norm} into CSR order
__global__ void k_scatter(const int* __restrict__ dst, const int* __restrict__ srcv,
                          const int* __restrict__ ety, const float* __restrict__ norm,
                          int* __restrict__ fill, uint2* __restrict__ erec) {
  int e = blockIdx.x * 256 + threadIdx.x;
  int pos = atomicAdd(&fill[dst[e]], 1);
  erec[pos] = make_uint2((unsigned)srcv[e] | ((unsigned)ety[e] << 16),
                         __float_as_uint(norm[e]));
}

// ---------------- per-node aggregation: one wave per node ----------------
// lane owns 4 CONSECUTIVE features [lane*4 .. lane*4+3] x 8 bases.
// All accumulator indexing is compile-time (rule #20: no runtime idx -> VGPRs).
__global__ __launch_bounds__(256) void k_agg(
    const __bf16* __restrict__ xb, const float* __restrict__ w_comp,
    const int* __restrict__ offs, const int* __restrict__ fin,
    const uint2* __restrict__ erec, __bf16* __restrict__ A) {
  __shared__ float wc[NUM_RELS * NUM_BASES];   // 512 floats
  int t = threadIdx.x;
  wc[t] = w_comp[t];
  wc[t + 256] = w_comp[t + 256];
  __syncthreads();

  int wid = t >> 6, lane = t & 63;
  int node = blockIdx.x * 4 + wid;             // grid 12500 -> exactly 50000

  f32x2 acc[NUM_BASES][2];
#pragma unroll
  for (int b = 0; b < NUM_BASES; ++b) {
    acc[b][0] = f32x2{0.f, 0.f};
    acc[b][1] = f32x2{0.f, 0.f};
  }

  int i0 = offs[node];
  int cnt = fin[node] - i0;
  const uint2* rp = erec + i0;
  int lo4 = lane * 4;

  int i = 0;
  for (; i + 4 <= cnt; i += 4) {
    uint2 r[4];
#pragma unroll
    for (int j = 0; j < 4; ++j) r[j] = rp[i + j];
    uint2 xv[4];
#pragma unroll
    for (int j = 0; j < 4; ++j)
      xv[j] = *(const uint2*)(xb + (size_t)(r[j].x & 0xffff) * IN_FEAT + lo4);
#pragma unroll
    for (int j = 0; j < 4; ++j) {
      int et = r[j].x >> 16;
      float nm = __uint_as_float(r[j].y);
      f32x2 v0 = {__uint_as_float(xv[j].x << 16) * nm,
                  __uint_as_float(xv[j].x & 0xffff0000u) * nm};
      f32x2 v1 = {__uint_as_float(xv[j].y << 16) * nm,
                  __uint_as_float(xv[j].y & 0xffff0000u) * nm};
      f32x4 cl = *(const f32x4*)&wc[et * 8];
      f32x4 ch = *(const f32x4*)&wc[et * 8 + 4];
#pragma unroll
      for (int b = 0; b < 4; ++b) {
        acc[b][0] += v0 * cl[b];
        acc[b][1] += v1 * cl[b];
        acc[b + 4][0] += v0 * ch[b];
        acc[b + 4][1] += v1 * ch[b];
      }
    }
  }
  for (; i < cnt; ++i) {
    uint2 r = rp[i];
    int et = r.x >> 16;
    float nm = __uint_as_float(r.y);
    uint2 xv = *(const uint2*)(xb + (size_t)(r.x & 0xffff) * IN_FEAT + lo4);
    f32x2 v0 = {__uint_as_float(xv.x << 16) * nm,
                __uint_as_float(xv.x & 0xffff0000u) * nm};
    f32x2 v1 = {__uint_as_float(xv.y << 16) * nm,
                __uint_as_float(xv.y & 0xffff0000u) * nm};
    f32x4 cl = *(const f32x4*)&wc[et * 8];
    f32x4 ch = *(const f32x4*)&wc[et * 8 + 4];
#pragma unroll
    for (int b = 0; b < 4; ++b) {
      acc[b][0] += v0 * cl[b];
      acc[b][1] += v1 * cl[b];
      acc[b + 4][0] += v0 * ch[b];
      acc[b + 4][1] += v1 * ch[b];
    }
  }

  __bf16* Ar = A + (size_t)node * KAGG + lo4;
#pragma unroll
  for (int b = 0; b < NUM_BASES; ++b) {
    bf16x4 o;
    o[0] = (__bf16)acc[b][0][0];
    o[1] = (__bf16)acc[b][0][1];
    o[2] = (__bf16)acc[b][1][0];
    o[3] = (__bf16)acc[b][1][1];
    *(bf16x4*)(Ar + b * 256) = o;
  }
}

// ---------------- weight prep: Wt[o][r] = Wcat[r][o] in bf16 ----------------
__global__ void k_prepw(const float* __restrict__ weight, const float* __restrict__ loop_w,
                        __bf16* __restrict__ Wt) {
  int o = blockIdx.x;
  int t = threadIdx.x;
#pragma unroll
  for (int c = 0; c < 9; ++c) {
    int r = c * 256 + t;
    float v = (r < 2048) ? weight[(size_t)r * 256 + o]
                         : loop_w[(size_t)(r - 2048) * 256 + o];
    Wt[(size_t)o * KTOT + r] = (__bf16)v;
  }
}

// ---------------- GEMM: out[M][256] = [A | xb] @ Wt^T + bias, relu ----------
// 128x256 tile, 4 waves (each 64 rows x 128 cols = 4x8 frags), BK=32.
// LDS XOR-swizzled via pre-swizzled global source (rule 21):
//   physical chunk p of row holds logical chunk q = p ^ ((row>>1)&3).
__global__ __launch_bounds__(256, 2) void k_gemm(const __bf16* __restrict__ A,
                                                 const __bf16* __restrict__ xb,
                                                 const __bf16* __restrict__ Wt,
                                                 const float* __restrict__ bias,
                                                 float* __restrict__ out) {
  __shared__ __align__(16) __bf16 sA[128 * 32];   // 8KB
  __shared__ __align__(16) __bf16 sB[256 * 32];   // 16KB

  int t = threadIdx.x;
  int wid = t >> 6, lane = t & 63;
  int tm = blockIdx.x;
  int wr = wid >> 1, wc = wid & 1;
  int rfw = __builtin_amdgcn_readfirstlane(wid);

  f32x4 acc[4][8];
#pragma unroll
  for (int m = 0; m < 4; ++m)
#pragma unroll
    for (int n = 0; n < 8; ++n) acc[m][n] = f32x4{0.f, 0.f, 0.f, 0.f};

  int frow = lane & 15;
  int kb = (((lane >> 4) ^ ((frow >> 1) & 3)) << 4);  // swizzled k-slice byte off

  // precompute per-thread staging sources (swizzled global chunk addresses)
  const __bf16* gaP[2];
  const __bf16* gxP[2];
#pragma unroll
  for (int it = 0; it < 2; ++it) {
    int L = it * 256 + t;
    int row = L >> 2;
    int q = (L & 3) ^ ((row >> 1) & 3);
    gaP[it] = A + (size_t)(tm * 128 + row) * KAGG + q * 8;
    gxP[it] = xb + (size_t)(tm * 128 + row) * IN_FEAT + q * 8;
  }
  const __bf16* gbP[4];
#pragma unroll
  for (int it = 0; it < 4; ++it) {
    int L = it * 256 + t;
    int row = L >> 2;
    int q = (L & 3) ^ ((row >> 1) & 3);
    gbP[it] = Wt + (size_t)row * KTOT + q * 8;
  }

#define KSTEP(A0, A1, K0)                                                   \
  do {                                                                      \
    gload_lds16((A0), (char*)sA + rfw * 1024);                              \
    gload_lds16((A1), (char*)sA + 4096 + rfw * 1024);                       \
    _Pragma("unroll") for (int it = 0; it < 4; ++it)                        \
        gload_lds16(gbP[it] + (K0), (char*)sB + (it * 256 + rfw * 64) * 16);\
    __syncthreads();                                                        \
    bf16x8 af[4], bfr[8];                                                   \
    _Pragma("unroll") for (int m = 0; m < 4; ++m)                           \
        af[m] = *(const bf16x8*)((const char*)sA +                          \
                                 (wr * 64 + m * 16 + frow) * 64 + kb);      \
    _Pragma("unroll") for (int n = 0; n < 8; ++n)                           \
        bfr[n] = *(const bf16x8*)((const char*)sB +                         \
                                  (wc * 128 + n * 16 + frow) * 64 + kb);    \
    _Pragma("unroll") for (int m = 0; m < 4; ++m)                           \
        _Pragma("unroll") for (int n = 0; n < 8; ++n)                       \
            acc[m][n] = __builtin_amdgcn_mfma_f32_16x16x32_bf16(            \
                af[m], bfr[n], acc[m][n], 0, 0, 0);                         \
    __syncthreads();                                                        \
  } while (0)

  for (int kt = 0; kt < 64; ++kt) {
    int k0 = kt * 32;
    KSTEP(gaP[0] + k0, gaP[1] + k0, k0);
  }
  for (int kt = 64; kt < 72; ++kt) {
    int k0 = kt * 32;
    int kx = k0 - KAGG;
    KSTEP(gxP[0] + kx, gxP[1] + kx, k0);
  }
#undef KSTEP

  // epilogue: C/D layout col = lane&15, row = (lane>>4)*4 + r
  int r0 = (lane >> 4) * 4;
  int c0 = lane & 15;
#pragma unroll
  for (int m = 0; m < 4; ++m) {
    int rowb = tm * 128 + wr * 64 + m * 16 + r0;
#pragma unroll
    for (int n = 0; n < 8; ++n) {
      int col = wc * 128 + n * 16 + c0;
      float bv = bias[col];
#pragma unroll
      for (int r = 0; r < 4; ++r) {
        int row = rowb + r;
        if (row < N_NODES) {
          float v = acc[m][n][r] + bv;
          out[(size_t)row * OUT_FEAT + col] = v > 0.f ? v : 0.f;
        }
      }
    }
  }
}

extern "C" void kernel_launch(void* const* d_in, const int* in_sizes, int n_in,
                              void* d_out, int out_size, void* d_ws, size_t ws_size,
                              hipStream_t stream) {
  const float* x      = (const float*)d_in[0];
  const int*   src    = (const int*)d_in[1];
  const int*   dst    = (const int*)d_in[2];
  const int*   ety    = (const int*)d_in[3];
  const float* norm   = (const float*)d_in[4];
  const float* weight = (const float*)d_in[5];
  const float* w_comp = (const float*)d_in[6];
  const float* h_bias = (const float*)d_in[7];
  const float* loop_w = (const float*)d_in[8];
  float* out = (float*)d_out;

  char* ws = (char*)d_ws;
  __bf16* A  = (__bf16*)ws;                                 // 205MB
  size_t off = (size_t)MP * KAGG * 2;
  __bf16* xb = (__bf16*)(ws + off);                         // 25.6MB
  off += (size_t)MP * IN_FEAT * 2;
  __bf16* Wt = (__bf16*)(ws + off);                         // 1.18MB
  off += (size_t)256 * KTOT * 2;
  uint2* erec = (uint2*)(ws + off);                         // 6.4MB
  off += (size_t)N_EDGES * 8;
  int* deg   = (int*)(ws + off);
  int* offs  = deg + N_NODES;
  int* fill  = offs + N_NODES;
  int* bsum  = fill + N_NODES;

  hipMemsetAsync(deg, 0, N_NODES * sizeof(int), stream);
  k_prex<<<(N_NODES * IN_FEAT / 8) / 256, 256, 0, stream>>>(x, xb);
  k_count<<<N_EDGES / 256, 256, 0, stream>>>(dst, deg);
  k_scan1<<<SCAN_BLKS, 256, 0, stream>>>(deg, offs, bsum);
  k_scan3<<<SCAN_BLKS, 256, 0, stream>>>(offs, bsum, fill);
  k_scatter<<<N_EDGES / 256, 256, 0, stream>>>(dst, src, ety, norm, fill, erec);
  k_agg<<<N_NODES / 4, 256, 0, stream>>>(xb, w_comp, offs, fill, erec, A);
  k_prepw<<<256, 256, 0, stream>>>(weight, loop_w, Wt);
  k_gemm<<<MP / 128, 256, 0, stream>>>(A, xb, Wt, h_bias, out);
}

// Round 5
// 317.188 us; speedup vs baseline: 1.7484x; 1.0081x over previous
//
#include <hip/hip_runtime.h>
#include <hip/hip_bf16.h>
#include <stdint.h>

#define N_NODES 50000
#define N_EDGES 800000
#define IN_FEAT 256
#define OUT_FEAT 256
#define NUM_RELS 64
#define NUM_BASES 8
#define KTOT 2304           // Wt row stride: 8*256 + 256 self-loop
#define KAGG 2048           // A matrix K (bases only)
#define MP 50048            // 391 * 128 padded M
#define SCAN_BLKS 196

typedef __attribute__((ext_vector_type(8))) __bf16 bf16x8;
typedef __attribute__((ext_vector_type(4))) __bf16 bf16x4;
typedef __attribute__((ext_vector_type(4))) float f32x4;
typedef __attribute__((ext_vector_type(2))) float f32x2;

static __device__ __forceinline__ void gload_lds16(const void* g, void* l) {
  auto gp = (const __attribute__((address_space(1))) void*)(uintptr_t)g;
  auto lp = (__attribute__((address_space(3))) void*)(uint32_t)(uintptr_t)l;
  __builtin_amdgcn_global_load_lds(gp, lp, 16, 0, 0);
}

// ---------------- x -> bf16 ----------------
__global__ void k_prex(const float* __restrict__ x, __bf16* __restrict__ xb) {
  int i = blockIdx.x * 256 + threadIdx.x;
  const float4* xp = (const float4*)x;
  float4 u = xp[i * 2], v = xp[i * 2 + 1];
  bf16x8 o;
  o[0] = (__bf16)u.x; o[1] = (__bf16)u.y; o[2] = (__bf16)u.z; o[3] = (__bf16)u.w;
  o[4] = (__bf16)v.x; o[5] = (__bf16)v.y; o[6] = (__bf16)v.z; o[7] = (__bf16)v.w;
  *(bf16x8*)(xb + (size_t)i * 8) = o;
}

// ---------------- CSR build ----------------
__global__ void k_count(const int* __restrict__ dst, int* __restrict__ deg) {
  int e = blockIdx.x * 256 + threadIdx.x;
  atomicAdd(&deg[dst[e]], 1);
}

__global__ void k_scan1(const int* __restrict__ deg, int* __restrict__ offs,
                        int* __restrict__ bsum) {
  __shared__ int s[256];
  int t = threadIdx.x;
  int i = blockIdx.x * 256 + t;
  int v = (i < N_NODES) ? deg[i] : 0;
  s[t] = v;
  __syncthreads();
  for (int d = 1; d < 256; d <<= 1) {
    int y = (t >= d) ? s[t - d] : 0;
    __syncthreads();
    s[t] += y;
    __syncthreads();
  }
  if (i < N_NODES) offs[i] = s[t] - v;
  if (t == 255) bsum[blockIdx.x] = s[255];
}

// adds cross-block base (computed in-block from bsum) and inits fill
__global__ void k_scan3(int* __restrict__ offs, const int* __restrict__ bsum,
                        int* __restrict__ fill) {
  __shared__ int s[256];
  int t = threadIdx.x;
  s[t] = (t < SCAN_BLKS && t < blockIdx.x) ? bsum[t] : 0;
  __syncthreads();
  for (int d = 128; d; d >>= 1) {
    if (t < d) s[t] += s[t + d];
    __syncthreads();
  }
  int base = s[0];
  int i = blockIdx.x * 256 + t;
  if (i < N_NODES) {
    int o = offs[i] + base;
    offs[i] = o;
    fill[i] = o;
  }
}

// scatter packed edge records {src|ety<<16, norm} into CSR order
__global__ void k_scatter(const int* __restrict__ dst, const int* __restrict__ srcv,
                          const int* __restrict__ ety, const float* __restrict__ norm,
                          int* __restrict__ fill, uint2* __restrict__ erec) {
  int e = blockIdx.x * 256 + threadIdx.x;
  int pos = atomicAdd(&fill[dst[e]], 1);
  erec[pos] = make_uint2((unsigned)srcv[e] | ((unsigned)ety[e] << 16),
                         __float_as_uint(norm[e]));
}

// ---------------- per-node aggregation: one wave per node ----------------
// lane owns 4 CONSECUTIVE features [lane*4 .. lane*4+3] x 8 bases.
// All accumulator indexing is compile-time (rule #20: no runtime idx -> VGPRs).
__global__ __launch_bounds__(256) void k_agg(
    const __bf16* __restrict__ xb, const float* __restrict__ w_comp,
    const int* __restrict__ offs, const int* __restrict__ fin,
    const uint2* __restrict__ erec, __bf16* __restrict__ A) {
  __shared__ float wc[NUM_RELS * NUM_BASES];   // 512 floats
  int t = threadIdx.x;
  wc[t] = w_comp[t];
  wc[t + 256] = w_comp[t + 256];
  __syncthreads();

  int wid = t >> 6, lane = t & 63;
  int node = blockIdx.x * 4 + wid;             // grid 12500 -> exactly 50000

  f32x2 acc[NUM_BASES][2];
#pragma unroll
  for (int b = 0; b < NUM_BASES; ++b) {
    acc[b][0] = f32x2{0.f, 0.f};
    acc[b][1] = f32x2{0.f, 0.f};
  }

  int i0 = offs[node];
  int cnt = fin[node] - i0;
  const uint2* rp = erec + i0;
  int lo4 = lane * 4;

  int i = 0;
  for (; i + 4 <= cnt; i += 4) {
    uint2 r[4];
#pragma unroll
    for (int j = 0; j < 4; ++j) r[j] = rp[i + j];
    uint2 xv[4];
#pragma unroll
    for (int j = 0; j < 4; ++j)
      xv[j] = *(const uint2*)(xb + (size_t)(r[j].x & 0xffff) * IN_FEAT + lo4);
#pragma unroll
    for (int j = 0; j < 4; ++j) {
      int et = r[j].x >> 16;
      float nm = __uint_as_float(r[j].y);
      f32x2 v0 = {__uint_as_float(xv[j].x << 16) * nm,
                  __uint_as_float(xv[j].x & 0xffff0000u) * nm};
      f32x2 v1 = {__uint_as_float(xv[j].y << 16) * nm,
                  __uint_as_float(xv[j].y & 0xffff0000u) * nm};
      f32x4 cl = *(const f32x4*)&wc[et * 8];
      f32x4 ch = *(const f32x4*)&wc[et * 8 + 4];
#pragma unroll
      for (int b = 0; b < 4; ++b) {
        acc[b][0] += v0 * cl[b];
        acc[b][1] += v1 * cl[b];
        acc[b + 4][0] += v0 * ch[b];
        acc[b + 4][1] += v1 * ch[b];
      }
    }
  }
  for (; i < cnt; ++i) {
    uint2 r = rp[i];
    int et = r.x >> 16;
    float nm = __uint_as_float(r.y);
    uint2 xv = *(const uint2*)(xb + (size_t)(r.x & 0xffff) * IN_FEAT + lo4);
    f32x2 v0 = {__uint_as_float(xv.x << 16) * nm,
                __uint_as_float(xv.x & 0xffff0000u) * nm};
    f32x2 v1 = {__uint_as_float(xv.y << 16) * nm,
                __uint_as_float(xv.y & 0xffff0000u) * nm};
    f32x4 cl = *(const f32x4*)&wc[et * 8];
    f32x4 ch = *(const f32x4*)&wc[et * 8 + 4];
#pragma unroll
    for (int b = 0; b < 4; ++b) {
      acc[b][0] += v0 * cl[b];
      acc[b][1] += v1 * cl[b];
      acc[b + 4][0] += v0 * ch[b];
      acc[b + 4][1] += v1 * ch[b];
    }
  }

  __bf16* Ar = A + (size_t)node * KAGG + lo4;
#pragma unroll
  for (int b = 0; b < NUM_BASES; ++b) {
    bf16x4 o;
    o[0] = (__bf16)acc[b][0][0];
    o[1] = (__bf16)acc[b][0][1];
    o[2] = (__bf16)acc[b][1][0];
    o[3] = (__bf16)acc[b][1][1];
    *(bf16x4*)(Ar + b * 256) = o;
  }
}

// ---------------- weight prep: Wt[o][r] = Wcat[r][o] in bf16 ----------------
__global__ void k_prepw(const float* __restrict__ weight, const float* __restrict__ loop_w,
                        __bf16* __restrict__ Wt) {
  int o = blockIdx.x;
  int t = threadIdx.x;
#pragma unroll
  for (int c = 0; c < 9; ++c) {
    int r = c * 256 + t;
    float v = (r < 2048) ? weight[(size_t)r * 256 + o]
                         : loop_w[(size_t)(r - 2048) * 256 + o];
    Wt[(size_t)o * KTOT + r] = (__bf16)v;
  }
}

// ---------------- GEMM: out[M][256] = [A | xb] @ Wt^T + bias, relu ----------
// 128x256 tile, 4 waves (each 64 rows x 128 cols = 4x8 frags), BK=32.
// Double-buffered 2-phase loop (T3-minimum): STAGE(next,buf^1) issued before
// compute(buf); single barrier per K-step; next-stage HBM latency hides under
// ds_read+MFMA of the current step.
// LDS XOR-swizzle via pre-swizzled global source (rule 21), swizzled reads.
__global__ __launch_bounds__(256, 2) void k_gemm(const __bf16* __restrict__ A,
                                                 const __bf16* __restrict__ xb,
                                                 const __bf16* __restrict__ Wt,
                                                 const float* __restrict__ bias,
                                                 float* __restrict__ out) {
  __shared__ __align__(16) __bf16 sA[2 * 128 * 32];   // 2 x 8KB
  __shared__ __align__(16) __bf16 sB[2 * 256 * 32];   // 2 x 16KB

  int t = threadIdx.x;
  int wid = t >> 6, lane = t & 63;
  int tm = blockIdx.x;
  int wr = wid >> 1, wc = wid & 1;
  int rfw = __builtin_amdgcn_readfirstlane(wid);

  f32x4 acc[4][8];
#pragma unroll
  for (int m = 0; m < 4; ++m)
#pragma unroll
    for (int n = 0; n < 8; ++n) acc[m][n] = f32x4{0.f, 0.f, 0.f, 0.f};

  int frow = lane & 15;
  int kb = (((lane >> 4) ^ ((frow >> 1) & 3)) << 4);  // swizzled k-slice byte off

  // per-thread staging sources (swizzled global chunk addresses)
  const __bf16* gaP[2];
  const __bf16* gxP[2];
#pragma unroll
  for (int it = 0; it < 2; ++it) {
    int L = it * 256 + t;
    int row = L >> 2;
    int q = (L & 3) ^ ((row >> 1) & 3);
    gaP[it] = A + (size_t)(tm * 128 + row) * KAGG + q * 8;
    gxP[it] = xb + (size_t)(tm * 128 + row) * IN_FEAT + q * 8;
  }
  const __bf16* gbP[4];
#pragma unroll
  for (int it = 0; it < 4; ++it) {
    int L = it * 256 + t;
    int row = L >> 2;
    int q = (L & 3) ^ ((row >> 1) & 3);
    gbP[it] = Wt + (size_t)row * KTOT + q * 8;
  }

#define STAGE(KT, BUF)                                                        \
  do {                                                                        \
    int k0_ = (KT) * 32;                                                      \
    const __bf16 *a0_, *a1_;                                                  \
    if ((KT) < 64) { a0_ = gaP[0] + k0_; a1_ = gaP[1] + k0_; }                \
    else { int kx_ = k0_ - KAGG; a0_ = gxP[0] + kx_; a1_ = gxP[1] + kx_; }    \
    char* bA_ = (char*)sA + (BUF) * 8192;                                     \
    char* bB_ = (char*)sB + (BUF) * 16384;                                    \
    gload_lds16(a0_, bA_ + rfw * 1024);                                       \
    gload_lds16(a1_, bA_ + 4096 + rfw * 1024);                                \
    _Pragma("unroll") for (int it = 0; it < 4; ++it)                          \
        gload_lds16(gbP[it] + k0_, bB_ + (it * 256 + rfw * 64) * 16);         \
  } while (0)

#define COMPUTE(BUF)                                                          \
  do {                                                                        \
    const char* bA_ = (const char*)sA + (BUF) * 8192;                         \
    const char* bB_ = (const char*)sB + (BUF) * 16384;                        \
    bf16x8 af[4], bfr[8];                                                     \
    _Pragma("unroll") for (int m = 0; m < 4; ++m)                             \
        af[m] = *(const bf16x8*)(bA_ + (wr * 64 + m * 16 + frow) * 64 + kb);  \
    _Pragma("unroll") for (int n = 0; n < 8; ++n)                             \
        bfr[n] = *(const bf16x8*)(bB_ + (wc * 128 + n * 16 + frow) * 64 + kb);\
    _Pragma("unroll") for (int m = 0; m < 4; ++m)                             \
        _Pragma("unroll") for (int n = 0; n < 8; ++n)                         \
            acc[m][n] = __builtin_amdgcn_mfma_f32_16x16x32_bf16(              \
                af[m], bfr[n], acc[m][n], 0, 0, 0);                           \
  } while (0)

  STAGE(0, 0);
  __syncthreads();                    // drains vmcnt(0): buf0 ready
  int cur = 0;
  for (int kt = 0; kt < 71; ++kt) {
    STAGE(kt + 1, cur ^ 1);           // issue next tile early
    COMPUTE(cur);                     // ds_read + MFMA hide the stage latency
    __syncthreads();                  // vmcnt(0)+lgkmcnt(0)+barrier: next buf ready
    cur ^= 1;
  }
  COMPUTE(cur);
#undef STAGE
#undef COMPUTE

  // epilogue: C/D layout col = lane&15, row = (lane>>4)*4 + r
  int r0 = (lane >> 4) * 4;
  int c0 = lane & 15;
#pragma unroll
  for (int m = 0; m < 4; ++m) {
    int rowb = tm * 128 + wr * 64 + m * 16 + r0;
#pragma unroll
    for (int n = 0; n < 8; ++n) {
      int col = wc * 128 + n * 16 + c0;
      float bv = bias[col];
#pragma unroll
      for (int r = 0; r < 4; ++r) {
        int row = rowb + r;
        if (row < N_NODES) {
          float v = acc[m][n][r] + bv;
          out[(size_t)row * OUT_FEAT + col] = v > 0.f ? v : 0.f;
        }
      }
    }
  }
}

extern "C" void kernel_launch(void* const* d_in, const int* in_sizes, int n_in,
                              void* d_out, int out_size, void* d_ws, size_t ws_size,
                              hipStream_t stream) {
  const float* x      = (const float*)d_in[0];
  const int*   src    = (const int*)d_in[1];
  const int*   dst    = (const int*)d_in[2];
  const int*   ety    = (const int*)d_in[3];
  const float* norm   = (const float*)d_in[4];
  const float* weight = (const float*)d_in[5];
  const float* w_comp = (const float*)d_in[6];
  const float* h_bias = (const float*)d_in[7];
  const float* loop_w = (const float*)d_in[8];
  float* out = (float*)d_out;

  char* ws = (char*)d_ws;
  __bf16* A  = (__bf16*)ws;                                 // 205MB
  size_t off = (size_t)MP * KAGG * 2;
  __bf16* xb = (__bf16*)(ws + off);                         // 25.6MB
  off += (size_t)MP * IN_FEAT * 2;
  __bf16* Wt = (__bf16*)(ws + off);                         // 1.18MB
  off += (size_t)256 * KTOT * 2;
  uint2* erec = (uint2*)(ws + off);                         // 6.4MB
  off += (size_t)N_EDGES * 8;
  int* deg   = (int*)(ws + off);
  int* offs  = deg + N_NODES;
  int* fill  = offs + N_NODES;
  int* bsum  = fill + N_NODES;

  hipMemsetAsync(deg, 0, N_NODES * sizeof(int), stream);
  k_prex<<<(N_NODES * IN_FEAT / 8) / 256, 256, 0, stream>>>(x, xb);
  k_count<<<N_EDGES / 256, 256, 0, stream>>>(dst, deg);
  k_scan1<<<SCAN_BLKS, 256, 0, stream>>>(deg, offs, bsum);
  k_scan3<<<SCAN_BLKS, 256, 0, stream>>>(offs, bsum, fill);
  k_scatter<<<N_EDGES / 256, 256, 0, stream>>>(dst, src, ety, norm, fill, erec);
  k_agg<<<N_NODES / 4, 256, 0, stream>>>(xb, w_comp, offs, fill, erec, A);
  k_prepw<<<256, 256, 0, stream>>>(weight, loop_w, Wt);
  k_gemm<<<MP / 128, 256, 0, stream>>>(A, xb, Wt, h_bias, out);
}